// Round 11
// baseline (45.684 us; speedup 1.0000x reference)
//
#include <hip/hip_runtime.h>

// NoiseLearnModule: out = x + where(0<=bin<16, eps * sigmoid(params[f,bin]) * 0.1, 0)
// bin = searchsorted(bins[f], x, side='right') - 1
// x,eps [65536,256] f32; bins [256,17] f32; params [256*16] f32.
//
// R11: LDS-table design, all measured failure modes fixed:
//  - staging: coalesced global reads, transposed LDS writes with bank-spread
//    pads (bins rows 260: write bank (4e+f)%32 ~2-way; scale rows 257:
//    write bank ~(k+f)%32 ~2-4-way). No scattered global reads (R8/R9's
//    hidden cost), no 16-way transpose conflicts (R1/R7's hidden cost).
//  - scan: 17x ds_read_b128 from [e][f] serves U=2 float4 groups (8 elems).
//  - gather: f32 [16][257], bank (jc+4t+c)%32 — jc spreads banks.
//  - table prescaled by 0.1; epilogue = cndmask + fma.
//  - grid 1024 = exactly 4 blocks/CU at 34.1 KB LDS; 8 guard-free iters.

#define NFEAT 256
#define NBINS 16
#define NEDGE 17
#define BPAD  260              // bins row stride (mult of 4: keeps b128 16B-aligned)
#define SPAD  257              // scale row stride (odd: jc spreads banks)
#define NOISE_SCALE 0.1f

__global__ __launch_bounds__(256) void noise_learn_kernel(
    const float* __restrict__ x,
    const float* __restrict__ bins,
    const float* __restrict__ eps,
    const float* __restrict__ params,
    float* __restrict__ out,
    int total4)
{
    __shared__ float s_bins[NEDGE * BPAD];      // 17680 B, [e][f] padded
    __shared__ float s_scale[NBINS * SPAD];     // 16448 B, [k][f] padded

    const int t = threadIdx.x;

    // Bins: coalesced read bins[i], transposed write. Write bank =
    // (4e+f)%32 with e varying per lane -> ~2-way.
    #pragma unroll
    for (int i = t; i < NEDGE * NFEAT; i += 256) {     // 17 exact iters
        const float v = bins[i];
        const int f = i / NEDGE;
        const int e = i - f * NEDGE;
        s_bins[e * BPAD + f] = v;
    }

    // Scale: coalesced read params[i], prescaled sigmoid, transposed write.
    // Write bank = (257k+f)%32 = (k+f)%32 -> ~2-4-way.
    #pragma unroll
    for (int i = t; i < NFEAT * NBINS; i += 256) {     // 16 exact iters
        const float p = params[i];
        const int f = i >> 4;
        const int k = i & (NBINS - 1);
        s_scale[k * SPAD + f] = NOISE_SCALE / (1.0f + __expf(-p));
    }
    __syncthreads();

    const int nthreads = gridDim.x * 256;              // 262144, multiple of 64
    const int gid = blockIdx.x * 256 + t;
    const int fbase = (t & 63) * 4;                    // loop-invariant features

    // total4 = 4,194,304 = 262144 * 16 -> exactly 8 guard-free U=2 iters.
    for (int base = gid; base + nthreads < total4; base += 2 * nthreads) {
        const int g0 = base;
        const int g1 = base + nthreads;

        const float4 xa = reinterpret_cast<const float4*>(x)[g0];
        const float4 xb = reinterpret_cast<const float4*>(x)[g1];
        const float4 ea = reinterpret_cast<const float4*>(eps)[g0];
        const float4 eb = reinterpret_cast<const float4*>(eps)[g1];

        int a0 = 0, a1 = 0, a2 = 0, a3 = 0;
        int b0 = 0, b1 = 0, b2 = 0, b3 = 0;

        #pragma unroll
        for (int e = 0; e < NEDGE; ++e) {              // one b128 serves 8 elems
            const float4 be = *reinterpret_cast<const float4*>(&s_bins[e * BPAD + fbase]);
            a0 += (be.x <= xa.x) ? 1 : 0;
            a1 += (be.y <= xa.y) ? 1 : 0;
            a2 += (be.z <= xa.z) ? 1 : 0;
            a3 += (be.w <= xa.w) ? 1 : 0;
            b0 += (be.x <= xb.x) ? 1 : 0;
            b1 += (be.y <= xb.y) ? 1 : 0;
            b2 += (be.z <= xb.z) ? 1 : 0;
            b3 += (be.w <= xb.w) ? 1 : 0;
        }

        float4 oa, ob;
        {
            const int idx = a0 - 1;
            const int jc = idx < 0 ? 0 : (idx > NBINS - 1 ? NBINS - 1 : idx);
            float sc = s_scale[jc * SPAD + fbase + 0];
            sc = ((unsigned)idx < (unsigned)NBINS) ? sc : 0.0f;
            oa.x = fmaf(ea.x, sc, xa.x);
        }
        {
            const int idx = a1 - 1;
            const int jc = idx < 0 ? 0 : (idx > NBINS - 1 ? NBINS - 1 : idx);
            float sc = s_scale[jc * SPAD + fbase + 1];
            sc = ((unsigned)idx < (unsigned)NBINS) ? sc : 0.0f;
            oa.y = fmaf(ea.y, sc, xa.y);
        }
        {
            const int idx = a2 - 1;
            const int jc = idx < 0 ? 0 : (idx > NBINS - 1 ? NBINS - 1 : idx);
            float sc = s_scale[jc * SPAD + fbase + 2];
            sc = ((unsigned)idx < (unsigned)NBINS) ? sc : 0.0f;
            oa.z = fmaf(ea.z, sc, xa.z);
        }
        {
            const int idx = a3 - 1;
            const int jc = idx < 0 ? 0 : (idx > NBINS - 1 ? NBINS - 1 : idx);
            float sc = s_scale[jc * SPAD + fbase + 3];
            sc = ((unsigned)idx < (unsigned)NBINS) ? sc : 0.0f;
            oa.w = fmaf(ea.w, sc, xa.w);
        }
        {
            const int idx = b0 - 1;
            const int jc = idx < 0 ? 0 : (idx > NBINS - 1 ? NBINS - 1 : idx);
            float sc = s_scale[jc * SPAD + fbase + 0];
            sc = ((unsigned)idx < (unsigned)NBINS) ? sc : 0.0f;
            ob.x = fmaf(eb.x, sc, xb.x);
        }
        {
            const int idx = b1 - 1;
            const int jc = idx < 0 ? 0 : (idx > NBINS - 1 ? NBINS - 1 : idx);
            float sc = s_scale[jc * SPAD + fbase + 1];
            sc = ((unsigned)idx < (unsigned)NBINS) ? sc : 0.0f;
            ob.y = fmaf(eb.y, sc, xb.y);
        }
        {
            const int idx = b2 - 1;
            const int jc = idx < 0 ? 0 : (idx > NBINS - 1 ? NBINS - 1 : idx);
            float sc = s_scale[jc * SPAD + fbase + 2];
            sc = ((unsigned)idx < (unsigned)NBINS) ? sc : 0.0f;
            ob.z = fmaf(eb.z, sc, xb.z);
        }
        {
            const int idx = b3 - 1;
            const int jc = idx < 0 ? 0 : (idx > NBINS - 1 ? NBINS - 1 : idx);
            float sc = s_scale[jc * SPAD + fbase + 3];
            sc = ((unsigned)idx < (unsigned)NBINS) ? sc : 0.0f;
            ob.w = fmaf(eb.w, sc, xb.w);
        }

        reinterpret_cast<float4*>(out)[g0] = oa;
        reinterpret_cast<float4*>(out)[g1] = ob;
    }
}

extern "C" void kernel_launch(void* const* d_in, const int* in_sizes, int n_in,
                              void* d_out, int out_size, void* d_ws, size_t ws_size,
                              hipStream_t stream) {
    const float* x      = (const float*)d_in[0];
    const float* bins   = (const float*)d_in[1];
    const float* eps    = (const float*)d_in[2];
    const float* params = (const float*)d_in[3];
    float* out = (float*)d_out;

    const int total4 = out_size / 4;   // 4,194,304 = 1024*256*2*8 -> 8 exact iters
    dim3 block(256);
    dim3 grid(1024);                   // exactly 4 blocks/CU at 34.1 KB LDS
    noise_learn_kernel<<<grid, block, 0, stream>>>(x, bins, eps, params, out, total4);
}

// Round 12
// 39.005 us; speedup vs baseline: 1.1712x; 1.1712x over previous
//
#include <hip/hip_runtime.h>

// NoiseLearnModule: out = x + where(0<=bin<16, eps * sigmoid(params[f,bin]) * 0.1, 0)
// bin = searchsorted(bins[f], x, side='right') - 1
// x,eps [65536,256] f32; bins [256,17] f32; params [256*16] f32.
//
// R12 = R9 (zero-LDS, 1 feature/thread, fused cndmask scan+select, U=4) with
// the remat pathology attacked at TUPLE granularity: tables live in float4
// ext-vectors, each passed once through asm("" : "+v") after the prologue.
// Tuple asm-outputs are opaque -> the compiler cannot re-derive them from
// bins[]/params[] inside the loop (R9's VGPR=32 disease), and 4-wide tuples
// are regalloc-friendly (R10's 33 scalar pins fragmented into AGPR copies).

typedef float f32x4 __attribute__((ext_vector_type(4)));

#define NFEAT 256
#define NBINS 16
#define NEDGE 17
#define NOISE_SCALE 0.1f

__global__ __launch_bounds__(256, 4) void noise_learn_kernel(
    const float* __restrict__ x,
    const float* __restrict__ bins,
    const float* __restrict__ eps,
    const float* __restrict__ params,
    float* __restrict__ out,
    int total)
{
    const int t = threadIdx.x;               // == feature id

    // Prologue: tables -> register tuples.
    f32x4 e0, e1, e2, e3; float e16;
    {
        const float* br = bins + t * NEDGE;
        #pragma unroll
        for (int i = 0; i < 4; ++i) e0[i] = br[i];
        #pragma unroll
        for (int i = 0; i < 4; ++i) e1[i] = br[4 + i];
        #pragma unroll
        for (int i = 0; i < 4; ++i) e2[i] = br[8 + i];
        #pragma unroll
        for (int i = 0; i < 4; ++i) e3[i] = br[12 + i];
        e16 = br[16];
    }

    f32x4 s0, s1, s2, s3;                    // pre-scaled: 0.1 * sigmoid(p)
    {
        const float* pr = params + t * NBINS;
        #pragma unroll
        for (int i = 0; i < 4; ++i) s0[i] = NOISE_SCALE / (1.0f + __expf(-pr[i]));
        #pragma unroll
        for (int i = 0; i < 4; ++i) s1[i] = NOISE_SCALE / (1.0f + __expf(-pr[4 + i]));
        #pragma unroll
        for (int i = 0; i < 4; ++i) s2[i] = NOISE_SCALE / (1.0f + __expf(-pr[8 + i]));
        #pragma unroll
        for (int i = 0; i < 4; ++i) s3[i] = NOISE_SCALE / (1.0f + __expf(-pr[12 + i]));
    }

    // Tuple-granular anti-remat pins: each quad becomes an opaque VGPR tuple.
    asm volatile("" : "+v"(e0), "+v"(e1), "+v"(e2), "+v"(e3), "+v"(e16));
    asm volatile("" : "+v"(s0), "+v"(s1), "+v"(s2), "+v"(s3));

    const int n = gridDim.x * 256;           // multiple of 256 -> feature invariant
    const int gid = blockIdx.x * 256 + t;

// Fused scan+select chain: selects sg[clamp(count-1,0,15)]; valid = e0[0]<=x<e16.
#define PROC(xv, ev, res) do {                                           \
        float s = s0[0];                                                 \
        s = (e0[1] <= (xv)) ? s0[1] : s;                                 \
        s = (e0[2] <= (xv)) ? s0[2] : s;                                 \
        s = (e0[3] <= (xv)) ? s0[3] : s;                                 \
        s = (e1[0] <= (xv)) ? s1[0] : s;                                 \
        s = (e1[1] <= (xv)) ? s1[1] : s;                                 \
        s = (e1[2] <= (xv)) ? s1[2] : s;                                 \
        s = (e1[3] <= (xv)) ? s1[3] : s;                                 \
        s = (e2[0] <= (xv)) ? s2[0] : s;                                 \
        s = (e2[1] <= (xv)) ? s2[1] : s;                                 \
        s = (e2[2] <= (xv)) ? s2[2] : s;                                 \
        s = (e2[3] <= (xv)) ? s2[3] : s;                                 \
        s = (e3[0] <= (xv)) ? s3[0] : s;                                 \
        s = (e3[1] <= (xv)) ? s3[1] : s;                                 \
        s = (e3[2] <= (xv)) ? s3[2] : s;                                 \
        s = (e3[3] <= (xv)) ? s3[3] : s;                                 \
        const float v_ = (e0[0] <= (xv) && (xv) < e16) ? s : 0.0f;       \
        (res) = fmaf((ev), v_, (xv));                                    \
    } while (0)

    // total = 16,777,216 = 2048*256*4*8 -> exactly 8 guard-free iterations.
    for (int base = gid; base + 3 * n < total; base += 4 * n) {
        const int gA = base, gB = base + n, gC = base + 2 * n, gD = base + 3 * n;

        const float xA = x[gA], xB = x[gB], xC = x[gC], xD = x[gD];
        const float pA = eps[gA], pB = eps[gB], pC = eps[gC], pD = eps[gD];

        float rA, rB, rC, rD;
        PROC(xA, pA, rA);
        PROC(xB, pB, rB);
        PROC(xC, pC, rC);
        PROC(xD, pD, rD);

        out[gA] = rA;
        out[gB] = rB;
        out[gC] = rC;
        out[gD] = rD;
    }
#undef PROC
}

extern "C" void kernel_launch(void* const* d_in, const int* in_sizes, int n_in,
                              void* d_out, int out_size, void* d_ws, size_t ws_size,
                              hipStream_t stream) {
    const float* x      = (const float*)d_in[0];
    const float* bins   = (const float*)d_in[1];
    const float* eps    = (const float*)d_in[2];
    const float* params = (const float*)d_in[3];
    float* out = (float*)d_out;

    dim3 block(256);
    dim3 grid(2048);   // zero LDS; 8 iterations of U=4 per thread, no tail
    noise_learn_kernel<<<grid, block, 0, stream>>>(x, bins, eps, params, out, out_size);
}